// Round 6
// baseline (3059.523 us; speedup 1.0000x reference)
//
#include <hip/hip_runtime.h>
#include <hip/hip_bf16.h>
#include <math.h>

typedef __bf16 bf16_t;
typedef __bf16 bf16x8 __attribute__((ext_vector_type(8)));
typedef float  f32x4  __attribute__((ext_vector_type(4)));

#define TOKENS 8192
#define DIMV   768
#define INNERV 768
#define QKVW   2304
#define MLPW   3072
#define NSEQ   1024
#define NB     8
#define NH     12
#define DH     64

enum { EP_STORE = 0, EP_BIAS_RES = 1, EP_BIAS_GELU = 2 };

__device__ __forceinline__ void load_lds16(const void* g, void* l) {
  __builtin_amdgcn_global_load_lds(
      (const __attribute__((address_space(1))) void*)g,
      (__attribute__((address_space(3))) void*)l,
      16, 0, 0);
}

// ---------------- GEMM: C[M,N] = s * (A[M,K] * B[N,K]^T) + bias, bf16 in, f32 acc ----
// 256 thr = 4 waves (2x2), 128x128 tile, BK=32, mfma_f32_16x16x32_bf16.
// Staging: async global_load_lds width=16. Wave w lane l -> global row w*16+l/4,
// col (l&3)*8; LDS offset from wave base = l*16 B (contiguous, matches HW scatter).
__global__ __launch_bounds__(256)
void gemm_nt(const bf16_t* __restrict__ A, const bf16_t* __restrict__ B,
             const int K, const int N, const int mode,
             const float* __restrict__ sacc_p, const float sinvn, const float sbias,
             const float* __restrict__ bias,
             float* __restrict__ resid,
             bf16_t* __restrict__ outb)
{
  __shared__ __align__(16) bf16_t lsA[128 * 32];
  __shared__ __align__(16) bf16_t lsB[128 * 32];
  const int tid  = threadIdx.x;
  const int lane = tid & 63;
  const int wave = tid >> 6;
  const int wm = wave >> 1, wn = wave & 1;
  const int bm = blockIdx.x, bn = blockIdx.y;

  // async staging: wave covers rows [wave*16, wave*16+16) and +64
  const bf16_t* gA = A + (size_t)(bm * 128 + wave * 16 + (lane >> 2)) * K + (lane & 3) * 8;
  const bf16_t* gB = B + (size_t)(bn * 128 + wave * 16 + (lane >> 2)) * K + (lane & 3) * 8;
  bf16_t* dA = &lsA[(wave * 16) * 32];
  bf16_t* dB = &lsB[(wave * 16) * 32];

  f32x4 acc[4][4];
#pragma unroll
  for (int i = 0; i < 4; i++)
#pragma unroll
    for (int j = 0; j < 4; j++) acc[i][j] = (f32x4){0.f, 0.f, 0.f, 0.f};

  const int arow = (wm * 64 + (lane & 15)) * 32 + (lane >> 4) * 8;
  const int brow = (wn * 64 + (lane & 15)) * 32 + (lane >> 4) * 8;

  for (int kb = 0; kb < K; kb += 32) {
    __syncthreads();                    // prev iter's LDS reads complete
    load_lds16(gA + kb,                  dA);
    load_lds16(gA + kb + (size_t)64 * K, dA + 64 * 32);
    load_lds16(gB + kb,                  dB);
    load_lds16(gB + kb + (size_t)64 * K, dB + 64 * 32);
    __syncthreads();                    // staging complete (vmcnt drained by compiler)
    bf16x8 af[4], bfv[4];
#pragma unroll
    for (int i = 0; i < 4; i++) af[i]  = *(const bf16x8*)&lsA[arow + i * 16 * 32];
#pragma unroll
    for (int j = 0; j < 4; j++) bfv[j] = *(const bf16x8*)&lsB[brow + j * 16 * 32];
#pragma unroll
    for (int i = 0; i < 4; i++)
#pragma unroll
      for (int j = 0; j < 4; j++)
        acc[i][j] = __builtin_amdgcn_mfma_f32_16x16x32_bf16(af[i], bfv[j], acc[i][j], 0, 0, 0);
  }

  const float s = (*sacc_p) * sinvn + sbias;
  const int r0 = bm * 128 + wm * 64 + (lane >> 4) * 4;
  const int c0 = bn * 128 + wn * 64 + (lane & 15);
#pragma unroll
  for (int i = 0; i < 4; i++) {
#pragma unroll
    for (int j = 0; j < 4; j++) {
      const int col = c0 + j * 16;
#pragma unroll
      for (int r = 0; r < 4; r++) {
        const int row = r0 + i * 16 + r;
        const float v = acc[i][j][r] * s;
        const size_t idx = (size_t)row * N + col;
        if (mode == EP_STORE) {
          outb[idx] = (bf16_t)v;
        } else if (mode == EP_BIAS_RES) {
          resid[idx] += v + bias[col];
        } else {  // EP_BIAS_GELU (exact gelu)
          const float t = v + bias[col];
          outb[idx] = (bf16_t)(0.5f * t * (1.0f + erff(t * 0.70710678118654752f)));
        }
      }
    }
  }
}

// ---------------- LayerNorm: one block per row; f32 gamma/beta; bf16 out -------------
template <typename TIN>
__global__ __launch_bounds__(256)
void ln_kern(const TIN* __restrict__ x, const float* __restrict__ g,
             const float* __restrict__ b, bf16_t* __restrict__ y, const int W)
{
  const int row = blockIdx.x;
  const int tid = threadIdx.x;
  const TIN* xr = x + (size_t)row * W;
  float s = 0.f, s2 = 0.f;
  for (int i = tid; i < W; i += 256) {
    const float v = (float)xr[i];
    s += v; s2 += v * v;
  }
#pragma unroll
  for (int off = 32; off > 0; off >>= 1) {
    s  += __shfl_xor(s,  off, 64);
    s2 += __shfl_xor(s2, off, 64);
  }
  __shared__ float red[8];
  if ((tid & 63) == 0) { red[(tid >> 6) * 2] = s; red[(tid >> 6) * 2 + 1] = s2; }
  __syncthreads();
  const float ts  = red[0] + red[2] + red[4] + red[6];
  const float ts2 = red[1] + red[3] + red[5] + red[7];
  const float invW = 1.0f / (float)W;
  const float mean = ts * invW;
  const float var  = fmaxf(ts2 * invW - mean * mean, 0.f);
  const float rs   = rsqrtf(var + 1e-5f);
  bf16_t* yr = y + (size_t)row * W;
  for (int i = tid; i < W; i += 256) {
    const float v = ((float)xr[i] - mean) * rs * g[i] + b[i];
    yr[i] = (bf16_t)v;
  }
}

// ---------------- MFMA flash attention ----------------
__global__ __launch_bounds__(256)
void attn_mfma(const bf16_t* __restrict__ qkv, bf16_t* __restrict__ o)
{
  __shared__ __align__(16) bf16_t Ks[64][72];      // K [kv][d], +8 pad
  __shared__ __align__(16) bf16_t Vt[64][72];      // V^T [d][kv], +8 pad
  __shared__ __align__(16) bf16_t Pw[4][16][72];   // per-wave P [q][kv], +8 pad
  const int tid  = threadIdx.x;
  const int lane = tid & 63;
  const int wave = tid >> 6;
  const int quad = lane >> 4;
  const int l15  = lane & 15;
  const int qb = blockIdx.x, hh = blockIdx.y, bb = blockIdx.z;
  const size_t tokbase = (size_t)bb * NSEQ;

  const int qrow = qb * 64 + wave * 16 + l15;
  bf16x8 qf[2];
  {
    const bf16_t* qp = qkv + (tokbase + qrow) * QKVW + hh * DH;
    qf[0] = *(const bf16x8*)(qp + quad * 8);
    qf[1] = *(const bf16x8*)(qp + 32 + quad * 8);
  }

  f32x4 Ot[4];
#pragma unroll
  for (int i = 0; i < 4; i++) Ot[i] = (f32x4){0.f, 0.f, 0.f, 0.f};
  float m_r[4], l_r[4];
#pragma unroll
  for (int r = 0; r < 4; r++) { m_r[r] = -1e30f; l_r[r] = 0.f; }

  const int skv = tid & 63;
  const int sd  = (tid >> 6) * 16;

  for (int kt = 0; kt < NSEQ / 64; ++kt) {
    const bf16_t* kp = qkv + (tokbase + kt * 64 + skv) * QKVW + INNERV + hh * DH + sd;
    const bf16_t* vp = kp + INNERV;
    bf16x8 k0 = *(const bf16x8*)kp;
    bf16x8 k1 = *(const bf16x8*)(kp + 8);
    bf16x8 v0 = *(const bf16x8*)vp;
    bf16x8 v1 = *(const bf16x8*)(vp + 8);
    __syncthreads();
    *(bf16x8*)&Ks[skv][sd]     = k0;
    *(bf16x8*)&Ks[skv][sd + 8] = k1;
#pragma unroll
    for (int e = 0; e < 8; e++) { Vt[sd + e][skv] = v0[e]; Vt[sd + 8 + e][skv] = v1[e]; }
    __syncthreads();

    f32x4 st[4];
#pragma unroll
    for (int nt = 0; nt < 4; nt++) {
      bf16x8 b0 = *(const bf16x8*)&Ks[nt * 16 + l15][quad * 8];
      bf16x8 b1 = *(const bf16x8*)&Ks[nt * 16 + l15][32 + quad * 8];
      f32x4 c = (f32x4){0.f, 0.f, 0.f, 0.f};
      c = __builtin_amdgcn_mfma_f32_16x16x32_bf16(qf[0], b0, c, 0, 0, 0);
      c = __builtin_amdgcn_mfma_f32_16x16x32_bf16(qf[1], b1, c, 0, 0, 0);
      st[nt] = c;
    }

    float rmax[4];
#pragma unroll
    for (int r = 0; r < 4; r++) {
      float v = fmaxf(fmaxf(st[0][r], st[1][r]), fmaxf(st[2][r], st[3][r]));
      v = fmaxf(v, __shfl_xor(v, 1, 64));
      v = fmaxf(v, __shfl_xor(v, 2, 64));
      v = fmaxf(v, __shfl_xor(v, 4, 64));
      v = fmaxf(v, __shfl_xor(v, 8, 64));
      rmax[r] = v * 0.125f;
    }
    float alpha[4];
#pragma unroll
    for (int r = 0; r < 4; r++) {
      const float mnew = fmaxf(m_r[r], rmax[r]);
      alpha[r] = __expf(m_r[r] - mnew);
      m_r[r] = mnew;
    }
    float rsum[4] = {0.f, 0.f, 0.f, 0.f};
#pragma unroll
    for (int nt = 0; nt < 4; nt++) {
#pragma unroll
      for (int r = 0; r < 4; r++) {
        const float p = __expf(st[nt][r] * 0.125f - m_r[r]);
        rsum[r] += p;
        Pw[wave][quad * 4 + r][nt * 16 + l15] = (bf16_t)p;
      }
    }
#pragma unroll
    for (int r = 0; r < 4; r++) {
      float v = rsum[r];
      v += __shfl_xor(v, 1, 64);
      v += __shfl_xor(v, 2, 64);
      v += __shfl_xor(v, 4, 64);
      v += __shfl_xor(v, 8, 64);
      l_r[r] = l_r[r] * alpha[r] + v;
    }
#pragma unroll
    for (int dt = 0; dt < 4; dt++)
#pragma unroll
      for (int r = 0; r < 4; r++) Ot[dt][r] *= alpha[r];

    __syncthreads();

#pragma unroll
    for (int kk = 0; kk < 2; kk++) {
      bf16x8 pa = *(const bf16x8*)&Pw[wave][l15][kk * 32 + quad * 8];
#pragma unroll
      for (int dt = 0; dt < 4; dt++) {
        bf16x8 vb = *(const bf16x8*)&Vt[dt * 16 + l15][kk * 32 + quad * 8];
        Ot[dt] = __builtin_amdgcn_mfma_f32_16x16x32_bf16(pa, vb, Ot[dt], 0, 0, 0);
      }
    }
  }

  float inv[4];
#pragma unroll
  for (int r = 0; r < 4; r++) inv[r] = 1.0f / l_r[r];
#pragma unroll
  for (int dt = 0; dt < 4; dt++) {
#pragma unroll
    for (int r = 0; r < 4; r++) {
      const int q = qb * 64 + wave * 16 + quad * 4 + r;
      const int d = dt * 16 + l15;
      o[(tokbase + q) * INNERV + hh * DH + d] = (bf16_t)(Ot[dt][r] * inv[r]);
    }
  }
}

// ---------------- ternary quant helpers (f32 weights in) ----------------
__global__ __launch_bounds__(64)
void zero_kern(float* __restrict__ p)
{
  p[threadIdx.x] = 0.f;
}

__global__ __launch_bounds__(256)
void absmean_kern(const float* __restrict__ w, const long n, float* __restrict__ acc)
{
  const int tid = threadIdx.x;
  float s = 0.f;
  const size_t stride = (size_t)256 * gridDim.x * 4;
  for (size_t i = ((size_t)blockIdx.x * 256 + tid) * 4; i < (size_t)n; i += stride) {
    f32x4 t = *(const f32x4*)(w + i);
    s += fabsf(t[0]) + fabsf(t[1]) + fabsf(t[2]) + fabsf(t[3]);
  }
#pragma unroll
  for (int off = 32; off > 0; off >>= 1) s += __shfl_xor(s, off, 64);
  __shared__ float red[4];
  if ((tid & 63) == 0) red[tid >> 6] = s;
  __syncthreads();
  if (tid == 0) atomicAdd(acc, red[0] + red[1] + red[2] + red[3]);
}

__global__ __launch_bounds__(256)
void quant_kern(const float* __restrict__ w, bf16_t* __restrict__ wq,
                const int n, const float* __restrict__ acc, const float invn)
{
  const int i = blockIdx.x * 256 + threadIdx.x;
  if (i >= n) return;
  const float s = (*acc) * invn + 1e-8f;
  float q = rintf(w[i] / s);  // round-half-even, matches jnp.round
  q = fminf(1.f, fmaxf(-1.f, q));
  wq[i] = (bf16_t)q;
}

__global__ __launch_bounds__(256)
void copyf_kern(const float* __restrict__ in, float* __restrict__ out, const int n4)
{
  const int i = blockIdx.x * 256 + threadIdx.x;
  if (i < n4) ((f32x4*)out)[i] = ((const f32x4*)in)[i];
}

__global__ __launch_bounds__(256)
void f2b_kern(const float* __restrict__ in, bf16_t* __restrict__ out, const int n)
{
  const int i = blockIdx.x * 256 + threadIdx.x;
  if (i < n) out[i] = (bf16_t)in[i];
}

// ---------------- driver ----------------
extern "C" void kernel_launch(void* const* d_in, const int* in_sizes, int n_in,
                              void* d_out, int out_size, void* d_ws, size_t ws_size,
                              hipStream_t stream)
{
  // ALL inputs are float32 (per reference setup_inputs dtypes).
  const float* x     = (const float*)d_in[0];
  const float* ln1_g = (const float*)d_in[1];
  const float* ln1_b = (const float*)d_in[2];
  const float* Wqkv  = (const float*)d_in[3];
  const float* ln2_g = (const float*)d_in[4];
  const float* ln2_b = (const float*)d_in[5];
  const float* Wo    = (const float*)d_in[6];
  const float* bo    = (const float*)d_in[7];
  const float* fg1   = (const float*)d_in[8];
  const float* fb1   = (const float*)d_in[9];
  const float* W1    = (const float*)d_in[10];
  const float* b1    = (const float*)d_in[11];
  const float* fg2   = (const float*)d_in[12];
  const float* fb2   = (const float*)d_in[13];
  const float* W2    = (const float*)d_in[14];
  const float* b2    = (const float*)d_in[15];

  char* ws = (char*)d_ws;
  size_t off = 0;
  float*  sacc  = (float*)(ws + off);  off += 256;                         // scale sums; [63] stays 0
  float*  h     = (float*)(ws + off);  off += (size_t)TOKENS * DIMV * 4;   // 25.2 MB residual stream
  bf16_t* bigA  = (bf16_t*)(ws + off); off += (size_t)TOKENS * MLPW * 2;   // 50.3 MB LN outs / attn out
  bf16_t* bigB  = (bf16_t*)(ws + off); off += (size_t)TOKENS * MLPW * 2;   // 50.3 MB qkv / gelu out
  bf16_t* q_qkv = (bf16_t*)(ws + off); off += (size_t)QKVW * DIMV * 2;
  bf16_t* q_o   = (bf16_t*)(ws + off); off += (size_t)DIMV * INNERV * 2;
  bf16_t* q_1   = (bf16_t*)(ws + off); off += (size_t)MLPW * DIMV * 2;
  bf16_t* q_2   = (bf16_t*)(ws + off); off += (size_t)DIMV * MLPW * 2;     // total ~140 MB

  bf16_t* obuf   = bigA;                              // attn out (12.6 MB)
  bf16_t* ln2out = bigA + (size_t)TOKENS * INNERV;    // LN2 out

  zero_kern<<<1, 64, 0, stream>>>(sacc);
  copyf_kern<<<TOKENS * DIMV / 4 / 256, 256, 0, stream>>>(x, h, TOKENS * DIMV / 4);

  for (int lyr = 0; lyr < 6; ++lyr) {
    const float* wqkv_l = Wqkv + (size_t)lyr * QKVW * DIMV;
    const float* wo_l   = Wo   + (size_t)lyr * DIMV * INNERV;
    const float* w1_l   = W1   + (size_t)lyr * MLPW * DIMV;
    const float* w2_l   = W2   + (size_t)lyr * DIMV * MLPW;
    const float *sq, *so, *s1, *s2p;
    float iq, io, i1, i2, bq, bo2, bb1v, bb2v;
    if (lyr < 5) {
      absmean_kern<<<256, 256, 0, stream>>>(wqkv_l, (long)QKVW * DIMV, &sacc[lyr * 4 + 0]);
      absmean_kern<<<256, 256, 0, stream>>>(wo_l,   (long)DIMV * INNERV, &sacc[lyr * 4 + 1]);
      absmean_kern<<<256, 256, 0, stream>>>(w1_l,   (long)MLPW * DIMV, &sacc[lyr * 4 + 2]);
      absmean_kern<<<256, 256, 0, stream>>>(w2_l,   (long)DIMV * MLPW, &sacc[lyr * 4 + 3]);
      quant_kern<<<QKVW * DIMV / 256, 256, 0, stream>>>(wqkv_l, q_qkv, QKVW * DIMV, &sacc[lyr * 4 + 0], 1.0f / (QKVW * DIMV));
      quant_kern<<<DIMV * INNERV / 256, 256, 0, stream>>>(wo_l, q_o, DIMV * INNERV, &sacc[lyr * 4 + 1], 1.0f / (DIMV * INNERV));
      quant_kern<<<MLPW * DIMV / 256, 256, 0, stream>>>(w1_l, q_1, MLPW * DIMV, &sacc[lyr * 4 + 2], 1.0f / (MLPW * DIMV));
      quant_kern<<<DIMV * MLPW / 256, 256, 0, stream>>>(w2_l, q_2, DIMV * MLPW, &sacc[lyr * 4 + 3], 1.0f / (DIMV * MLPW));
      sq = &sacc[lyr * 4 + 0]; iq = 1.0f / (QKVW * DIMV); bq = 1e-8f;
      so = &sacc[lyr * 4 + 1]; io = 1.0f / (DIMV * INNERV); bo2 = 1e-8f;
      s1 = &sacc[lyr * 4 + 2]; i1 = 1.0f / (MLPW * DIMV); bb1v = 1e-8f;
      s2p = &sacc[lyr * 4 + 3]; i2 = 1.0f / (DIMV * MLPW); bb2v = 1e-8f;
    } else {
      // last layer: plain weights, bf16-cast, scale 1.0
      f2b_kern<<<QKVW * DIMV / 256, 256, 0, stream>>>(wqkv_l, q_qkv, QKVW * DIMV);
      f2b_kern<<<DIMV * INNERV / 256, 256, 0, stream>>>(wo_l, q_o, DIMV * INNERV);
      f2b_kern<<<MLPW * DIMV / 256, 256, 0, stream>>>(w1_l, q_1, MLPW * DIMV);
      f2b_kern<<<DIMV * MLPW / 256, 256, 0, stream>>>(w2_l, q_2, DIMV * MLPW);
      sq = so = s1 = s2p = &sacc[63];  // contains 0
      iq = io = i1 = i2 = 0.f;
      bq = bo2 = bb1v = bb2v = 1.0f;   // s = 0*0 + 1 = 1
    }

    // attention sub-block
    ln_kern<float><<<TOKENS, 256, 0, stream>>>(h, ln1_g + lyr * DIMV, ln1_b + lyr * DIMV, bigA, DIMV);
    gemm_nt<<<dim3(64, QKVW / 128), 256, 0, stream>>>(bigA, q_qkv, DIMV, QKVW, EP_STORE, sq, iq, bq, nullptr, nullptr, bigB);
    attn_mfma<<<dim3(NSEQ / 64, NH, NB), 256, 0, stream>>>(bigB, obuf);
    ln_kern<bf16_t><<<TOKENS, 256, 0, stream>>>(obuf, ln2_g + lyr * INNERV, ln2_b + lyr * INNERV, ln2out, INNERV);
    gemm_nt<<<dim3(64, DIMV / 128), 256, 0, stream>>>(ln2out, q_o, INNERV, DIMV, EP_BIAS_RES, so, io, bo2, bo + lyr * DIMV, h, nullptr);
    // FF sub-block
    ln_kern<float><<<TOKENS, 256, 0, stream>>>(h, fg1 + lyr * DIMV, fb1 + lyr * DIMV, bigA, DIMV);
    gemm_nt<<<dim3(64, MLPW / 128), 256, 0, stream>>>(bigA, q_1, DIMV, MLPW, EP_BIAS_GELU, s1, i1, bb1v, b1 + lyr * MLPW, nullptr, bigB);
    ln_kern<bf16_t><<<TOKENS, 256, 0, stream>>>(bigB, fg2 + lyr * MLPW, fb2 + lyr * MLPW, bigA, MLPW);
    gemm_nt<<<dim3(64, DIMV / 128), 256, 0, stream>>>(bigA, q_2, MLPW, DIMV, EP_BIAS_RES, s2p, i2, bb2v, b2 + lyr * DIMV, h, nullptr);
  }

  // OUTPUT IS FLOAT32 (reference returns f32) — copy residual stream directly.
  copyf_kern<<<TOKENS * DIMV / 4 / 256, 256, 0, stream>>>(h, (float*)d_out, TOKENS * DIMV / 4);
}